// Round 7
// baseline (747.234 us; speedup 1.0000x reference)
//
#include <hip/hip_runtime.h>

// ReLU-RNN B=8192, T=1024, I=7, H=100, O=1 — 2-wave H-split, hidden exchange.
//
// v8: v7 proved the H-split saves MFMA time but its exchange cost ~650cy/step
// (serial write->lgkm->barrier->read(120cy)->assemble->MFMA). v8 hides it:
//  - FULL-FRAGMENT ownership: wave0 owns ti{0,4,1,5} -> produces hf0,hf1
//    whole; wave1 owns ti{2,6,3} -> produces hf2,hf3 whole (incl. x/bias
//    tail; only wave1 loads x). Partner frags = one ds_read_b128 each,
//    NO assemble VALU; own frags never round-trip LDS.
//  - kt-ordering covers read latency: each wave runs the kt blocks that
//    consume its OWN fragments first (wave0: kt0,kt1 = 8 MFMA ~155cy;
//    wave1: kt2,kt3 = 6 ~117cy) while the partner reads (issued right
//    after the previous barrier) retire.
//  - early pack/write: in the last kt group, the accs feeding the first
//    produced fragment are computed first -> pack+ds_write overlaps the
//    remaining MFMAs. Pre-barrier tail = 1 pack + 1 write + lgkmcnt.
// One s_barrier per step (raw; manual lgkmcnt so x-prefetch vmcnt never
// drains). Double-buffered exchange slots by (t+1)&1 parity.
// 512 blocks x 128 thr = 1024 waves = 1 wave/SIMD chip-wide.
//
// Permuted-index scheme unchanged from v1 (verified):
//   D (ti,q,r) [n'=16ti+4q+r, batch m=lane&15] -> B slot k'=32kt+8q+jj;
//   hf[kt] = {pack(acc[kt]), pack(acc[kt+4])}; kt=3 jj>=4 carries x0..x6,bias.

typedef _Float16 half8 __attribute__((ext_vector_type(8)));
typedef float f32x4 __attribute__((ext_vector_type(4)));
typedef unsigned u32x4 __attribute__((ext_vector_type(4)));

static __device__ __forceinline__ unsigned pkrtz(float a, float b) {
    return __builtin_bit_cast(unsigned, __builtin_amdgcn_cvt_pkrtz(a, b));
}
// 4-byte-aligned float4 load (x rows have stride 7 floats)
static __device__ __forceinline__ f32x4 ld4(const float* p) {
    typedef f32x4 __attribute__((aligned(4))) f32x4a;
    return *(const f32x4a*)p;
}
// relu-pack two f32x4 accs into one complete 16B B-fragment (RTZ-exact:
// relu-after-pack == pack-after-relu, verified since v2)
static __device__ __forceinline__ u32x4 pack_relu4(f32x4 a, f32x4 b) {
    u32x4 u = { pkrtz(a[0], a[1]), pkrtz(a[2], a[3]),
                pkrtz(b[0], b[1]), pkrtz(b[2], b[3]) };
    const u32x4 zz = {0u, 0u, 0u, 0u};
    half8 h = __builtin_elementwise_max(__builtin_bit_cast(half8, u),
                                        __builtin_bit_cast(half8, zz));
    return __builtin_bit_cast(u32x4, h);
}

#define MFMA16(a, b, c) __builtin_amdgcn_mfma_f32_16x16x32_f16(a, b, c, 0, 0, 0)
#define LGKM0() asm volatile("s_waitcnt lgkmcnt(0)" ::: "memory")
#define FENCE() asm volatile("" ::: "memory")

__constant__ int kTI[2][4] = {{0, 4, 1, 5}, {2, 6, 3, 0}};

template<int WID>
static __device__ __forceinline__ void rnn_half(
    const int l, const int lm, const int q, const bool q1,
    const float* __restrict__ x,
    const float* __restrict__ W_ih, const float* __restrict__ W_hh,
    const float* __restrict__ b_ih, const float* __restrict__ b_hh,
    const float* __restrict__ W_fc, const float* __restrict__ b_fc,
    float* __restrict__ out,
    u32x4 (*xch)[4][64], float* red)
{
    constexpr int NT = (WID == 0) ? 4 : 3;   // wave0: ti{0,4,1,5}; wave1: ti{2,6,3}

    // ---- W' fragments for this wave's ti set (v1 mapping, row subset) ----
    half8 w[NT][4];
#pragma unroll
    for (int i = 0; i < NT; ++i) {
        const int ti = (WID == 0) ? ((i & 1) * 4 + (i >> 1))      // 0,4,1,5
                                  : (i == 0 ? 2 : (i == 1 ? 6 : 3)); // 2,6,3
        const int np = 16 * ti + lm;                 // output row n'
#pragma unroll
        for (int kt = 0; kt < 4; ++kt) {
            half8 hw;
#pragma unroll
            for (int jj = 0; jj < 8; ++jj) {
                float v = 0.f;
                if (np < 100) {
                    if (jj < 4) {                    // h slot, p = 16kt+4q+jj
                        int p = 16 * kt + 4 * q + jj;
                        if (p < 100) v = W_hh[np * 100 + p];
                    } else if (kt < 3) {             // h slot, p = 16(kt+4)+4q+(jj-4)
                        int p = 16 * (kt + 4) + 4 * q + (jj - 4);
                        if (p < 100) v = W_hh[np * 100 + p];
                    } else {                         // kt==3, jj>=4: x / bias slots
                        if (q == 0)      v = W_ih[np * 7 + (jj - 4)];
                        else if (q == 1) v = (jj < 7) ? W_ih[np * 7 + jj]
                                             : (b_ih[np] + b_hh[np]);
                    }
                }
                hw[jj] = (_Float16)v;
            }
            w[i][kt] = hw;
        }
    }

    const u32x4 zz = {0u, 0u, 0u, 0u};
    const f32x4 kZ = {0.f, 0.f, 0.f, 0.f};

    // ---- wave1 only: x addressing + depth-4 raw prefetch ring ----
    const float* xr = x + (size_t)(blockIdx.x * 16 + lm) * 7168;
    const int xo = q1 ? 3 : 0;
    f32x4 xv[4];
    if constexpr (WID == 1) {
#pragma unroll
        for (int s = 1; s <= 4; ++s) xv[s & 3] = ld4(xr + s * 7 + xo);
    }

    // ---- prologue: t=0 fragments. h=0 -> hf0/1/2 = 0; hf3 = {0,0,x0,bias}
    half8 hfA, hfB;            // this wave's OWN two fragments (regs)
    u32x4 rdA, rdB;            // partner's two fragments (LDS reads in flight)
    {
        u32x4 d0 = zz, d1 = zz;
        if constexpr (WID == 1) {
            f32x4 v = ld4(xr + xo);
            float a_ = q1 ? v.y : v.x, b_ = q1 ? v.z : v.y;
            float c_ = q1 ? v.w : v.z, e_ = q1 ? 1.0f : v.w;
            d1.z = pkrtz(a_, b_); d1.w = pkrtz(c_, e_);
        }
        hfA = __builtin_bit_cast(half8, d0);
        hfB = __builtin_bit_cast(half8, d1);
        // publish own t=0 fragments to slot 0
        xch[0][WID * 2 + 0][l] = d0;
        xch[0][WID * 2 + 1][l] = d1;
        LGKM0();
        __builtin_amdgcn_s_barrier();
        FENCE();
        rdA = xch[0][(WID ^ 1) * 2 + 0][l];
        rdB = xch[0][(WID ^ 1) * 2 + 1][l];
    }

    f32x4 acc[NT];

    for (int t = 0; t < 1024; ++t) {
        const int pn = (t + 1) & 1;              // slot for step t+1 fragments

        const half8 hp0 = __builtin_bit_cast(half8, rdA);   // partner frag A
        const half8 hp1 = __builtin_bit_cast(half8, rdB);   // partner frag B

        if constexpr (WID == 0) {
            // own kts first (hf0=hfA, hf1=hfB): reads retire underneath
            acc[0] = MFMA16(w[0][0], hfA, kZ);
            acc[1] = MFMA16(w[1][0], hfA, kZ);
            acc[2] = MFMA16(w[2][0], hfA, kZ);
            acc[3] = MFMA16(w[3][0], hfA, kZ);
            acc[0] = MFMA16(w[0][1], hfB, acc[0]);
            acc[1] = MFMA16(w[1][1], hfB, acc[1]);
            acc[2] = MFMA16(w[2][1], hfB, acc[2]);
            acc[3] = MFMA16(w[3][1], hfB, acc[3]);
            // partner kts (hf2=hp0, hf3=hp1); lgkmcnt lands here
            acc[0] = MFMA16(w[0][2], hp0, acc[0]);
            acc[1] = MFMA16(w[1][2], hp0, acc[1]);
            acc[2] = MFMA16(w[2][2], hp0, acc[2]);
            acc[3] = MFMA16(w[3][2], hp0, acc[3]);
            acc[0] = MFMA16(w[0][3], hp1, acc[0]);
            acc[1] = MFMA16(w[1][3], hp1, acc[1]);
            // hf0_next = pack(acc[ti0], acc[ti4]) — write overlaps last MFMAs
            u32x4 d0 = pack_relu4(acc[0], acc[1]);
            xch[pn][0][l] = d0;
            acc[2] = MFMA16(w[2][3], hp1, acc[2]);
            acc[3] = MFMA16(w[3][3], hp1, acc[3]);
            u32x4 d1 = pack_relu4(acc[2], acc[3]);
            xch[pn][1][l] = d1;
            hfA = __builtin_bit_cast(half8, d0);
            hfB = __builtin_bit_cast(half8, d1);
        } else {
            // own kts first (hf2=hfA, hf3=hfB)
            acc[0] = MFMA16(w[0][2], hfA, kZ);
            acc[1] = MFMA16(w[1][2], hfA, kZ);
            acc[2] = MFMA16(w[2][2], hfA, kZ);
            acc[0] = MFMA16(w[0][3], hfB, acc[0]);
            acc[1] = MFMA16(w[1][3], hfB, acc[1]);
            acc[2] = MFMA16(w[2][3], hfB, acc[2]);
            // partner kts (hf0=hp0, hf1=hp1)
            acc[0] = MFMA16(w[0][0], hp0, acc[0]);
            acc[1] = MFMA16(w[1][0], hp0, acc[1]);
            acc[2] = MFMA16(w[2][0], hp0, acc[2]);
            acc[0] = MFMA16(w[0][1], hp1, acc[0]);
            acc[1] = MFMA16(w[1][1], hp1, acc[1]);
            // hf2_next = pack(acc[ti2], acc[ti6])
            u32x4 d2 = pack_relu4(acc[0], acc[1]);
            xch[pn][2][l] = d2;
            acc[2] = MFMA16(w[2][1], hp1, acc[2]);
            // hf3_next: relu'd acc[ti3] + raw x_{t+1}/bias words
            const int s = (t + 1) & 3;
            f32x4 v = xv[s];
            float a_ = q1 ? v.y : v.x, b_ = q1 ? v.z : v.y;
            float c_ = q1 ? v.w : v.z, e_ = q1 ? 1.0f : v.w;
            u32x4 d3;
            d3.x = pkrtz(fmaxf(acc[2][0], 0.f), fmaxf(acc[2][1], 0.f));
            d3.y = pkrtz(fmaxf(acc[2][2], 0.f), fmaxf(acc[2][3], 0.f));
            d3.z = pkrtz(a_, b_);
            d3.w = pkrtz(c_, e_);
            xch[pn][3][l] = d3;
            // refill slot s with x_{t+5} raw (consumed 4 steps from now)
            int tn = t + 5; if (tn > 1023) tn = 1023;
            xv[s] = ld4(xr + tn * 7 + xo);
            hfA = __builtin_bit_cast(half8, d2);
            hfB = __builtin_bit_cast(half8, d3);
        }

        LGKM0();                         // own writes visible
        __builtin_amdgcn_s_barrier();
        FENCE();
        rdA = xch[pn][(WID ^ 1) * 2 + 0][l];   // partner frags for step t+1
        rdB = xch[pn][(WID ^ 1) * 2 + 1][l];
    }

    // ---- epilogue: acc = pre-relu h_T rows for own ti set ----
    float sum = 0.f;
#pragma unroll
    for (int i = 0; i < NT; ++i) {
        const int ti = (WID == 0) ? ((i & 1) * 4 + (i >> 1))
                                  : (i == 0 ? 2 : (i == 1 ? 6 : 3));
#pragma unroll
        for (int r = 0; r < 4; ++r) {
            const int np = 16 * ti + 4 * q + r;
            const float wf = (np < 100) ? W_fc[np] : 0.f;
            sum += wf * fmaxf(acc[i][r], 0.f);
        }
    }
    if constexpr (WID == 1) red[l] = sum;
    LGKM0();
    __builtin_amdgcn_s_barrier();
    FENCE();
    if constexpr (WID == 0) {
        float s2 = sum + red[l];
        s2 += __shfl_xor(s2, 16, 64);   // reduce across the 4 q-lanes of row lm
        s2 += __shfl_xor(s2, 32, 64);
        if (q == 0) out[blockIdx.x * 16 + lm] = s2 + b_fc[0];
    }
}

__global__ __launch_bounds__(128, 1)
void rnn_wave(const float* __restrict__ x,
              const float* __restrict__ W_ih,
              const float* __restrict__ W_hh,
              const float* __restrict__ b_ih,
              const float* __restrict__ b_hh,
              const float* __restrict__ W_fc,
              const float* __restrict__ b_fc,
              float* __restrict__ out) {
    __shared__ u32x4 xch[2][4][64];   // [parity][frag hf0..hf3][lane] 8 KB
    __shared__ float red[64];

    const int l  = threadIdx.x & 63;
    const int wv = threadIdx.x >> 6;     // wave 0/1 -> different SIMDs
    const int lm = l & 15;
    const int q  = l >> 4;
    const bool q1 = (q == 1);

    if (wv == 0)
        rnn_half<0>(l, lm, q, q1, x, W_ih, W_hh, b_ih, b_hh, W_fc, b_fc,
                    out, xch, red);
    else
        rnn_half<1>(l, lm, q, q1, x, W_ih, W_hh, b_ih, b_hh, W_fc, b_fc,
                    out, xch, red);
}

extern "C" void kernel_launch(void* const* d_in, const int* in_sizes, int n_in,
                              void* d_out, int out_size, void* d_ws, size_t ws_size,
                              hipStream_t stream) {
    const float* x    = (const float*)d_in[0];
    const float* W_ih = (const float*)d_in[1];
    const float* W_hh = (const float*)d_in[2];
    const float* b_ih = (const float*)d_in[3];
    const float* b_hh = (const float*)d_in[4];
    const float* W_fc = (const float*)d_in[5];
    const float* b_fc = (const float*)d_in[6];
    float* out = (float*)d_out;

    rnn_wave<<<dim3(512), dim3(128), 0, stream>>>(x, W_ih, W_hh, b_ih, b_hh, W_fc, b_fc, out);
}